// Round 1
// baseline (116.459 us; speedup 1.0000x reference)
//
#include <hip/hip_runtime.h>
#include <hip/hip_bf16.h>

// Problem constants (from reference setup_inputs)
#define RR 3
#define BB 2
#define NN 2048
#define DD 128
#define HH 4
#define HD 32
#define LEAKY 0.2f
#define LN_EPS 1e-5f

using f32x4  = __attribute__((ext_vector_type(4))) float;
using bf16x8 = __attribute__((ext_vector_type(8))) short;

__device__ __forceinline__ float leakyf(float x) { return x > 0.0f ? x : LEAKY * x; }

// ---------------------------------------------------------------------------
// Kernel 1: Wh = H @ W  per (r,b,h); store Wh^T as bf16 [r,b,h][f][n];
// also e_src/e_dst = Wh . a_src/a_dst  (fp32).
// grid = R*B*HH*(N/64) = 768 blocks, 256 threads.
// ---------------------------------------------------------------------------
__global__ __launch_bounds__(256) void wh_kernel(
    const float* __restrict__ H, const float* __restrict__ W,
    const float* __restrict__ a_src, const float* __restrict__ a_dst,
    float* __restrict__ es, float* __restrict__ ed,
    __hip_bfloat16* __restrict__ whT)
{
    const int bid = blockIdx.x;
    const int nt = bid & 31;          // N/64 tiles
    const int h  = (bid >> 5) & 3;
    const int b  = (bid >> 7) & 1;
    const int r  = bid >> 8;
    const int n0 = nt << 6;
    const int t  = threadIdx.x;

    __shared__ __align__(16) float Hs[64 * 128];
    __shared__ __align__(16) float Ws[128 * 32];

    const float* Hb = H + ((long)b * NN + n0) * DD;
#pragma unroll
    for (int k = 0; k < 8; ++k) {
        int f4 = t + 256 * k;
        ((float4*)Hs)[f4] = ((const float4*)Hb)[f4];
    }
    const float* Wb = W + (long)(r * HH + h) * DD * HD;
#pragma unroll
    for (int k = 0; k < 4; ++k) {
        int f4 = t + 256 * k;
        ((float4*)Ws)[f4] = ((const float4*)Wb)[f4];
    }
    __syncthreads();

    const int f  = t & 31;
    const int rg = t >> 5;
    const float av = a_src[(r * HH + h) * HD + f];
    const float dv = a_dst[(r * HH + h) * HD + f];
    const int rbh = (r * BB + b) * HH + h;

#pragma unroll
    for (int k = 0; k < 8; ++k) {
        const int row = rg * 8 + k;
        const float4* hrow = (const float4*)&Hs[row * 128];
        float acc = 0.0f;
#pragma unroll
        for (int d4 = 0; d4 < 32; ++d4) {
            float4 hv = hrow[d4];
            acc += hv.x * Ws[(d4 * 4 + 0) * 32 + f];
            acc += hv.y * Ws[(d4 * 4 + 1) * 32 + f];
            acc += hv.z * Ws[(d4 * 4 + 2) * 32 + f];
            acc += hv.w * Ws[(d4 * 4 + 3) * 32 + f];
        }
        // Wh^T store (bf16): [rbh][f][n]
        whT[((long)rbh * HD + f) * NN + n0 + row] = __float2bfloat16(acc);
        // reduce over f (32 lanes within half-wave) for e_src/e_dst
        float s = acc * av;
        float d = acc * dv;
#pragma unroll
        for (int m = 1; m < 32; m <<= 1) {
            s += __shfl_xor(s, m);
            d += __shfl_xor(d, m);
        }
        if (f == 0) {
            es[(long)rbh * NN + n0 + row] = s;
            ed[(long)rbh * NN + n0 + row] = d;
        }
    }
}

// ---------------------------------------------------------------------------
// Kernel 1b: med[rbh] = max_j e_dst[rbh][j]   (exact per-row softmax bound)
// grid = R*B*HH = 24 blocks, 256 threads
// ---------------------------------------------------------------------------
__global__ __launch_bounds__(256) void med_kernel(
    const float* __restrict__ ed, float* __restrict__ med)
{
    const int rbh = blockIdx.x;
    const int t = threadIdx.x;
    const float* e = ed + (long)rbh * NN;
    float m = -1e30f;
    for (int k = t; k < NN; k += 256) m = fmaxf(m, e[k]);
#pragma unroll
    for (int s = 1; s < 64; s <<= 1) m = fmaxf(m, __shfl_xor(m, s));
    __shared__ float red[4];
    if ((t & 63) == 0) red[t >> 6] = m;
    __syncthreads();
    if (t == 0) med[rbh] = fmaxf(fmaxf(red[0], red[1]), fmaxf(red[2], red[3]));
}

// ---------------------------------------------------------------------------
// Kernel 2: fused masked softmax + MFMA aggregation.
// Block = (r, b, i-tile of 16); 4 waves = 4 heads. Single pass over j
// (stability via the exact leaky(es+med) bound; denominator via ones-MFMA).
// grid = R*B*(N/16) = 768 blocks, 256 threads.
// Writes partial[r][b*N+i][128] = (alpha @ Wh) per relation (un-averaged).
// ---------------------------------------------------------------------------
__global__ __launch_bounds__(256) void gat_attn_kernel(
    const int* __restrict__ A, const float* __restrict__ es,
    const float* __restrict__ ed, const float* __restrict__ med,
    const __hip_bfloat16* __restrict__ whT, float* __restrict__ partial)
{
    const int bid = blockIdx.x;
    const int it = bid & 127;             // N/16 = 128 tiles
    const int b  = (bid >> 7) & 1;
    const int r  = bid >> 8;
    const int i0 = it << 4;
    const int tid = threadIdx.x;
    const int h = tid >> 6;               // wave = head
    const int l = tid & 63;
    const int jlane = l & 31;
    const int rowhalf = l >> 5;           // 0/1

    // per-wave p-tile: 16 rows x 32 j, padded row stride 40 bf16 (80 B)
    __shared__ __align__(16) __hip_bfloat16 ptile[4][16 * 40];
    __hip_bfloat16* pt = &ptile[h][0];

    const int rbh = (r * BB + b) * HH + h;
    const float* esb = es + (long)rbh * NN + i0;
    const float* edb = ed + (long)rbh * NN;
    const float meds = med[rbh];
    const long  abase = ((long)(r * BB + b) * NN + i0) * NN;
    const __hip_bfloat16* wb = whT + (long)rbh * HD * NN;

    float esv[8], Mv[8];
#pragma unroll
    for (int p = 0; p < 8; ++p) {
        float e = esb[p * 2 + rowhalf];
        esv[p] = e;
        Mv[p] = leakyf(e + meds);         // exact upper bound of row max
    }

    f32x4 acc0 = {0.f, 0.f, 0.f, 0.f};
    f32x4 acc1 = {0.f, 0.f, 0.f, 0.f};
    f32x4 accD = {0.f, 0.f, 0.f, 0.f};
    bf16x8 ones;
#pragma unroll
    for (int i = 0; i < 8; ++i) ones[i] = (short)0x3F80;  // bf16 1.0

    const int frow = l & 15;
    const int kg   = l >> 4;
    const __hip_bfloat16* ptread = pt + frow * 40 + kg * 8;

    for (int jc = 0; jc < NN / 32; ++jc) {
        const int j0 = jc * 32;
        const float edv = edb[j0 + jlane];
#pragma unroll
        for (int p = 0; p < 8; ++p) {
            const int row = p * 2 + rowhalf;
            const int av = A[abase + (long)row * NN + j0 + jlane];
            float e = leakyf(esv[p] + edv);
            float pv = (av > 0) ? __expf(e - Mv[p]) : 0.0f;
            pt[row * 40 + jlane] = __float2bfloat16(pv);
        }
        // same-wave LDS write -> read ordering
        asm volatile("s_waitcnt lgkmcnt(0)" ::: "memory");
        __builtin_amdgcn_sched_barrier(0);

        bf16x8 pfrag = *(const bf16x8*)ptread;                                  // A-frag: P 16x32
        bf16x8 b0 = *(const bf16x8*)(wb + (long)frow * NN + j0 + kg * 8);       // B-frag f 0..15
        bf16x8 b1 = *(const bf16x8*)(wb + (long)(16 + frow) * NN + j0 + kg * 8);// B-frag f 16..31

        acc0 = __builtin_amdgcn_mfma_f32_16x16x32_bf16(pfrag, b0, acc0, 0, 0, 0);
        acc1 = __builtin_amdgcn_mfma_f32_16x16x32_bf16(pfrag, b1, acc1, 0, 0, 0);
        accD = __builtin_amdgcn_mfma_f32_16x16x32_bf16(pfrag, ones, accD, 0, 0, 0);
    }

    // epilogue: alpha-normalize (divide by denominator), write partial
    const int fcol = l & 15;
#pragma unroll
    for (int reg = 0; reg < 4; ++reg) {
        const int row = (l >> 4) * 4 + reg;
        const float d = accD[reg];
        const float inv = (d > 0.0f) ? 1.0f / d : 0.0f;   // empty-row -> 0
        const long o = ((long)r * (BB * NN) + (long)b * NN + i0 + row) * DD + h * HD;
        partial[o + fcol]      = acc0[reg] * inv;
        partial[o + 16 + fcol] = acc1[reg] * inv;
    }
}

// ---------------------------------------------------------------------------
// Kernel 3: out = LayerNorm(H + mean_r partial).  One wave per row.
// grid = B*N/4 = 1024 blocks, 256 threads.
// ---------------------------------------------------------------------------
__global__ __launch_bounds__(256) void finalize_kernel(
    const float* __restrict__ H, const float* __restrict__ partial,
    const float* __restrict__ gamma, const float* __restrict__ beta,
    float* __restrict__ out)
{
    const int w = threadIdx.x >> 6;
    const int l = threadIdx.x & 63;
    const long row = (long)blockIdx.x * 4 + w;    // over B*N = 4096 rows
    const float2* hr = (const float2*)(H + row * DD);
    const float2* p0 = (const float2*)(partial + row * DD);
    const float2* p1 = (const float2*)(partial + ((long)BB * NN + row) * DD);
    const float2* p2 = (const float2*)(partial + ((long)2 * BB * NN + row) * DD);
    float2 hv = hr[l], a0 = p0[l], a1 = p1[l], a2 = p2[l];
    float x0 = hv.x + (a0.x + a1.x + a2.x) * (1.0f / RR);
    float x1 = hv.y + (a0.y + a1.y + a2.y) * (1.0f / RR);
    float s = x0 + x1, q = x0 * x0 + x1 * x1;
#pragma unroll
    for (int m = 1; m < 64; m <<= 1) {
        s += __shfl_xor(s, m);
        q += __shfl_xor(q, m);
    }
    const float mu  = s * (1.0f / DD);
    const float var = q * (1.0f / DD) - mu * mu;
    const float inv = rsqrtf(var + LN_EPS);
    const float g0 = gamma[l * 2], g1 = gamma[l * 2 + 1];
    const float b0 = beta[l * 2],  b1 = beta[l * 2 + 1];
    float2 o;
    o.x = (x0 - mu) * inv * g0 + b0;
    o.y = (x1 - mu) * inv * g1 + b1;
    ((float2*)(out + row * DD))[l] = o;
}

// ---------------------------------------------------------------------------
extern "C" void kernel_launch(void* const* d_in, const int* in_sizes, int n_in,
                              void* d_out, int out_size, void* d_ws, size_t ws_size,
                              hipStream_t stream)
{
    const float* H      = (const float*)d_in[0];
    const int*   A      = (const int*)d_in[1];
    const float* W      = (const float*)d_in[2];
    const float* a_src  = (const float*)d_in[3];
    const float* a_dst  = (const float*)d_in[4];
    const float* gamma  = (const float*)d_in[5];
    const float* beta   = (const float*)d_in[6];
    float* out = (float*)d_out;

    // workspace carve (≈9.9 MB total)
    char* ws = (char*)d_ws;
    float* partial = (float*)ws;                 ws += (size_t)RR * BB * NN * DD * 4;   // 6.29 MB
    float* es      = (float*)ws;                 ws += (size_t)RR * BB * HH * NN * 4;   // 196 KB
    float* ed      = (float*)ws;                 ws += (size_t)RR * BB * HH * NN * 4;   // 196 KB
    float* med     = (float*)ws;                 ws += 256;
    __hip_bfloat16* whT = (__hip_bfloat16*)ws;   ws += (size_t)RR * BB * HH * HD * NN * 2; // 3.15 MB

    wh_kernel<<<RR * BB * HH * (NN / 64), 256, 0, stream>>>(H, W, a_src, a_dst, es, ed, whT);
    med_kernel<<<RR * BB * HH, 256, 0, stream>>>(ed, med);
    gat_attn_kernel<<<RR * BB * (NN / 16), 256, 0, stream>>>(A, es, ed, med, whT, partial);
    finalize_kernel<<<BB * NN / 4, 256, 0, stream>>>(H, partial, gamma, beta, out);
}